// Round 12
// baseline (56.089 us; speedup 1.0000x reference)
//
#include <hip/hip_runtime.h>
#include <math.h>

#define IMG_W 512
#define IMG_HW (512 * 512)

typedef float f8v __attribute__((ext_vector_type(8)));
typedef float f2v __attribute__((ext_vector_type(2)));

// ---- DCT constants ----
#define A0c 0.35355339059327373f
#define C1c 0.4903926402016152f
#define C2c 0.46193976625564337f
#define C3c 0.41573480615127262f
#define C5c 0.27778511650980114f
#define C6c 0.19134171618254492f
#define C7c 0.09754516100806417f

// TRANSPOSED base JPEG tables: QT[v*8+u] = Q[u][v]. QUALITY=50 -> scaled==base.
__device__ const float QLUMT[64] = {
    16,12,14,14,18,24,49,72,
    11,12,13,17,22,35,64,92,
    10,14,16,22,37,55,78,95,
    16,19,24,29,56,64,87,98,
    24,26,40,51,68,81,103,112,
    40,58,57,87,109,104,121,100,
    51,60,69,80,103,113,120,103,
    61,55,56,62,77,92,101,99};
__device__ const float QCHRT[64] = {
    17,18,24,47,99,99,99,99,
    18,21,26,66,99,99,99,99,
    24,26,56,99,99,99,99,99,
    47,66,99,99,99,99,99,99,
    99,99,99,99,99,99,99,99,
    99,99,99,99,99,99,99,99,
    99,99,99,99,99,99,99,99,
    99,99,99,99,99,99,99,99};

__device__ __forceinline__ f2v mk2(float a, float b) { f2v r; r[0] = a; r[1] = b; return r; }

// In-place 8-point DCT-II, packed-f32 form (pairwise ops identical to scalar;
// backend maps <2 x float> arith to v_pk_*_f32 on gfx90a+).
__device__ __forceinline__ void fdct8(float v[8]) {
    f2v a01 = mk2(v[0], v[1]), b01 = mk2(v[7], v[6]);
    f2v a23 = mk2(v[2], v[3]), b23 = mk2(v[5], v[4]);
    f2v S01 = a01 + b01;            // s0, s1
    f2v S23 = a23 + b23;            // s2, s3
    f2v D01 = a01 - b01;            // d0, d1
    f2v D23 = a23 - b23;            // d2, d3
    f2v E = S01 + mk2(S23[1], S23[0]);   // e0 = s0+s3, e1 = s1+s2
    f2v F = S01 - mk2(S23[1], S23[0]);   // f0, f1
    f2v V04 = A0c * (mk2(E[0], E[0]) + mk2(E[1], -E[1]));
    v[0] = V04[0]; v[4] = V04[1];
    f2v V26 = mk2(C2c, C6c) * mk2(F[0], F[0]) + mk2(C6c, -C2c) * mk2(F[1], F[1]);
    v[2] = V26[0]; v[6] = V26[1];
    f2v d0b = mk2(D01[0], D01[0]), d1b = mk2(D01[1], D01[1]);
    f2v d2b = mk2(D23[0], D23[0]), d3b = mk2(D23[1], D23[1]);
    f2v V13 = mk2(C1c, C3c) * d0b + mk2(C3c, -C7c) * d1b
            + mk2(C5c, -C1c) * d2b + mk2(C7c, -C5c) * d3b;
    v[1] = V13[0]; v[3] = V13[1];
    f2v V57 = mk2(C5c, C7c) * d0b + mk2(-C1c, -C5c) * d1b
            + mk2(C7c, C3c) * d2b + mk2(C3c, -C1c) * d3b;
    v[5] = V57[0]; v[7] = V57[1];
}

// In-place 8-point inverse DCT, packed form.
__device__ __forceinline__ void idct8(float v[8]) {
    float g0 = v[0], g1 = v[1], g2 = v[2], g3 = v[3];
    float g4 = v[4], g5 = v[5], g6 = v[6], g7 = v[7];
    f2v EPM = A0c * (mk2(g0, g0) + mk2(g4, -g4));       // ep, em
    f2v T26 = mk2(C2c, C6c) * mk2(g2, g2) + mk2(C6c, -C2c) * mk2(g6, g6); // t26a, t26b
    f2v E01 = EPM + T26;                                 // e0 = ep+t26a, e1 = em+t26b
    f2v E23 = mk2(EPM[1], EPM[0]) - mk2(T26[1], T26[0]); // e2 = em-t26b, e3 = ep-t26a
    f2v g1b = mk2(g1, g1), g3b = mk2(g3, g3), g5b = mk2(g5, g5), g7b = mk2(g7, g7);
    f2v O01 = mk2(C1c, C3c) * g1b + mk2(C3c, -C7c) * g3b
            + mk2(C5c, -C1c) * g5b + mk2(C7c, -C5c) * g7b;
    f2v O23 = mk2(C5c, C7c) * g1b + mk2(-C1c, -C5c) * g3b
            + mk2(C7c, C3c) * g5b + mk2(C3c, -C1c) * g7b;
    f2v R01 = E01 + O01; f2v R76 = E01 - O01;
    f2v R23 = E23 + O23; f2v R54 = E23 - O23;
    v[0] = R01[0]; v[1] = R01[1]; v[7] = R76[0]; v[6] = R76[1];
    v[2] = R23[0]; v[3] = R23[1]; v[5] = R54[0]; v[4] = R54[1];
}

// soft quantize-dequantize on a PAIR of elements.
// deq = x + qh*tanh(15*(d - round(d))), d = x*rq, qh = 0.5*q
// (d*q==x fold: rcp error ~1e-7 relative, negligible vs 2e-2 tol)
#define K_EXP2 43.2808512266689f   // 30*log2(e)
__device__ __forceinline__ f2v softq2(f2v x, f2v qh, f2v rq) {
    f2v d = x * rq;
    f2v t = d - mk2(rintf(d[0]), rintf(d[1]));
    float ea = __builtin_amdgcn_exp2f(K_EXP2 * t[0]);
    float eb = __builtin_amdgcn_exp2f(K_EXP2 * t[1]);
    f2v e2 = mk2(ea, eb);
    f2v num = e2 - 1.0f;
    f2v th = num * mk2(__builtin_amdgcn_rcpf(e2[0] + 1.0f),
                       __builtin_amdgcn_rcpf(e2[1] + 1.0f));
    return x + qh * th;
}

// One wave = one 64x8 tile, all 3 channels serially through a wave-private
// LDS transpose region. Zero __syncthreads (in-order DS pipe per wave).
// Skew-12 layout: slot(v,b,x) = v*96 + b*12 + x -> strided b32 writes,
// CONTIGUOUS 16B-aligned reads (2x ds_read_b128 per transpose).
__global__ __launch_bounds__(256) void jpeg_kernel(const float* __restrict__ x,
                                                   float* __restrict__ out) {
    __shared__ float xpose[4][768];   // 12288 B per WG

    const int tid = threadIdx.x;
    const int wid = tid >> 6;
    const int lane = tid & 63;

    const int gw = blockIdx.x * 4 + wid;     // 0..16383
    const int bimg = gw >> 9;
    const int rem = gw & 511;
    const int gh = rem >> 3;                 // 8-row strip
    const int tx = rem & 7;                  // 64-col tile

    const int r = lane >> 3;                 // row within strip / freq v
    const int blk = lane & 7;                // 8x8 block within tile

    const size_t off = (size_t)bimg * 3 * IMG_HW +
                       (size_t)(gh * 8 + r) * IMG_W + tx * 64 + blk * 8;
    const float* base = x + off;

    const f8v Rv = *(const f8v*)(base);
    const f8v Gv = *(const f8v*)(base + IMG_HW);
    const f8v Bv = *(const f8v*)(base + 2 * IMG_HW);

    // q-tables in registers: qh = 0.5*q (transposed row r), rq = 1/q
    const f8v qLf = *(const f8v*)&QLUMT[r * 8];
    const f8v qCf = *(const f8v*)&QCHRT[r * 8];
    f8v qhL, rqL, qhC, rqC;
#pragma unroll
    for (int u = 0; u < 8; ++u) {
        qhL[u] = 0.5f * qLf[u];  rqL[u] = __builtin_amdgcn_rcpf(qLf[u]);
        qhC[u] = 0.5f * qCf[u];  rqC[u] = __builtin_amdgcn_rcpf(qCf[u]);
    }

    float* xp = xpose[wid];
    const int wbase = blk * 12 + r;          // write: xp[j*96 + wbase]
    const int rbase = r * 96 + blk * 12;     // read: xp[rbase + k], 16B aligned

    float g0[8], g1[8], g2[8];
    // ---- forward color, packed pairs ----
#pragma unroll
    for (int k = 0; k < 8; k += 2) {
        f2v R = mk2(Rv[k], Rv[k + 1]);
        f2v G = mk2(Gv[k], Gv[k + 1]);
        f2v B = mk2(Bv[k], Bv[k + 1]);
        f2v Y  = 0.299f * R + 0.587f * G + 0.114f * B - 0.5f;
        f2v Cb = -0.168736f * R - 0.331264f * G + 0.5f * B;
        f2v Cr = 0.5f * R - 0.418688f * G - 0.081312f * B;
        g0[k] = Y[0];  g0[k + 1] = Y[1];
        g1[k] = Cb[0]; g1[k + 1] = Cb[1];
        g2[k] = Cr[0]; g2[k + 1] = Cr[1];
    }

    // ---- per-channel chain (serial; wave-private LDS; in-order DS) ----
#pragma unroll
    for (int ch = 0; ch < 3; ++ch) {
        float* g = (ch == 0) ? g0 : (ch == 1) ? g1 : g2;
        const f8v qh = (ch == 0) ? qhL : qhC;
        const f8v rq = (ch == 0) ? rqL : rqC;

        fdct8(g);
        // transpose-1: strided writes, contiguous b128 reads
#pragma unroll
        for (int v = 0; v < 8; ++v) xp[v * 96 + wbase] = g[v];
        {
            float4 lo = *(const float4*)&xp[rbase];
            float4 hi = *(const float4*)&xp[rbase + 4];
            g[0] = lo.x; g[1] = lo.y; g[2] = lo.z; g[3] = lo.w;
            g[4] = hi.x; g[5] = hi.y; g[6] = hi.z; g[7] = hi.w;
        }
        fdct8(g);
        // softq (packed pairs)
#pragma unroll
        for (int u = 0; u < 8; u += 2) {
            f2v s = softq2(mk2(g[u], g[u + 1]), mk2(qh[u], qh[u + 1]), mk2(rq[u], rq[u + 1]));
            g[u] = s[0]; g[u + 1] = s[1];
        }
        idct8(g);
        // transpose-2: same pattern
#pragma unroll
        for (int xr = 0; xr < 8; ++xr) xp[xr * 96 + wbase] = g[xr];
        {
            float4 lo = *(const float4*)&xp[rbase];
            float4 hi = *(const float4*)&xp[rbase + 4];
            g[0] = lo.x; g[1] = lo.y; g[2] = lo.z; g[3] = lo.w;
            g[4] = hi.x; g[5] = hi.y; g[6] = hi.z; g[7] = hi.w;
        }
        idct8(g);
    }

    // ---- inverse color (packed) + nontemporal coalesced stores ----
    f8v Ro, Go, Bo;
#pragma unroll
    for (int k = 0; k < 8; k += 2) {
        f2v Y  = mk2(g0[k], g0[k + 1]) + 0.5f;
        f2v Cb = mk2(g1[k], g1[k + 1]);
        f2v Cr = mk2(g2[k], g2[k + 1]);
        f2v R = Y + 1.402f * Cr;
        f2v G = Y - 0.344136f * Cb - 0.714136f * Cr;
        f2v B = Y + 1.772f * Cb;
        f2v zero = mk2(0.0f, 0.0f), one = mk2(1.0f, 1.0f);
        R = __builtin_elementwise_min(__builtin_elementwise_max(R, zero), one);
        G = __builtin_elementwise_min(__builtin_elementwise_max(G, zero), one);
        B = __builtin_elementwise_min(__builtin_elementwise_max(B, zero), one);
        Ro[k] = R[0]; Ro[k + 1] = R[1];
        Go[k] = G[0]; Go[k + 1] = G[1];
        Bo[k] = B[0]; Bo[k + 1] = B[1];
    }
    float* obase = out + off;
    __builtin_nontemporal_store(Ro, (f8v*)(obase));
    __builtin_nontemporal_store(Go, (f8v*)(obase + IMG_HW));
    __builtin_nontemporal_store(Bo, (f8v*)(obase + 2 * IMG_HW));
}

extern "C" void kernel_launch(void* const* d_in, const int* in_sizes, int n_in,
                              void* d_out, int out_size, void* d_ws, size_t ws_size,
                              hipStream_t stream) {
    const float* x = (const float*)d_in[0];
    float* out = (float*)d_out;
    const int B = in_sizes[0] / (3 * IMG_HW);   // 32
    const int n_wg = B * 128;                   // one tile per wave, 4 waves/WG
    hipLaunchKernelGGL(jpeg_kernel, dim3(n_wg), dim3(256), 0, stream, x, out);
}

// Round 14
// 38.777 us; speedup vs baseline: 1.4465x; 1.4465x over previous
//
#include <hip/hip_runtime.h>
#include <math.h>

// ---- DCT constants (fp32) ----
#define A0c 0.35355339059327373f
#define C1c 0.4903926402016152f
#define C2c 0.46193976625564337f
#define C3c 0.41573480615127262f
#define C5c 0.27778511650980114f
#define C6c 0.19134171618254492f
#define C7c 0.09754516100806417f

#define IMG_W 512
#define IMG_HW (512 * 512)

typedef float f8v __attribute__((ext_vector_type(8)));

// base JPEG tables, ORIGINAL orientation (QUALITY=50 -> scaled == base)
__device__ const float QLUM[64] = {
    16,11,10,16,24,40,51,61,  12,12,14,19,26,58,60,55,
    14,13,16,24,40,57,69,56,  14,17,22,29,51,87,80,62,
    18,22,37,56,68,109,103,77, 24,35,55,64,81,104,113,92,
    49,64,78,87,103,121,120,101, 72,92,95,98,112,100,103,99};
__device__ const float QCHR[64] = {
    17,18,24,47,99,99,99,99,  18,21,26,66,99,99,99,99,
    24,26,56,99,99,99,99,99,  47,66,99,99,99,99,99,99,
    99,99,99,99,99,99,99,99,  99,99,99,99,99,99,99,99,
    99,99,99,99,99,99,99,99,  99,99,99,99,99,99,99,99};

// In-place 8-point DCT-II (scalar, R6-proven)
__device__ __forceinline__ void fdct8(float v[8]) {
    float s0 = v[0] + v[7], s1 = v[1] + v[6], s2 = v[2] + v[5], s3 = v[3] + v[4];
    float d0 = v[0] - v[7], d1 = v[1] - v[6], d2 = v[2] - v[5], d3 = v[3] - v[4];
    float e0 = s0 + s3, e1 = s1 + s2, f0 = s0 - s3, f1 = s1 - s2;
    v[0] = A0c * (e0 + e1);
    v[4] = A0c * (e0 - e1);
    v[2] = C2c * f0 + C6c * f1;
    v[6] = C6c * f0 - C2c * f1;
    v[1] = C1c * d0 + C3c * d1 + C5c * d2 + C7c * d3;
    v[3] = C3c * d0 - C7c * d1 - C1c * d2 - C5c * d3;
    v[5] = C5c * d0 - C1c * d1 + C7c * d2 + C3c * d3;
    v[7] = C7c * d0 - C5c * d1 + C3c * d2 - C1c * d3;
}

// In-place 8-point inverse (scalar, R6-proven)
__device__ __forceinline__ void idct8(float v[8]) {
    float g0 = v[0], g1 = v[1], g2 = v[2], g3 = v[3];
    float g4 = v[4], g5 = v[5], g6 = v[6], g7 = v[7];
    float ep = A0c * (g0 + g4), em = A0c * (g0 - g4);
    float t26a = C2c * g2 + C6c * g6;
    float t26b = C6c * g2 - C2c * g6;
    float e0 = ep + t26a, e1 = em + t26b, e2 = em - t26b, e3 = ep - t26a;
    float o0 = C1c * g1 + C3c * g3 + C5c * g5 + C7c * g7;
    float o1 = C3c * g1 - C7c * g3 - C1c * g5 - C5c * g7;
    float o2 = C5c * g1 - C1c * g3 + C7c * g5 + C3c * g7;
    float o3 = C7c * g1 - C5c * g3 + C3c * g5 - C1c * g7;
    v[0] = e0 + o0; v[7] = e0 - o0;
    v[1] = e1 + o1; v[6] = e1 - o1;
    v[2] = e2 + o2; v[5] = e2 - o2;
    v[3] = e3 + o3; v[4] = e3 - o3;
}

// soft quantize-dequantize: deq = x + qh*tanh(15t), qh = 0.5q, t = d - round(d)
// tanh via exp2 (R11/R12-proven): e2 = 2^(43.28*t), th = (e2-1)/(e2+1).
// (x*rq)*q == x fold: rcp relative error ~1e-7, negligible vs 2e-2 tol.
#define K_EXP2 43.2808512266689f
__device__ __forceinline__ float softq(float x, float qh, float rq) {
    float d = x * rq;
    float rn = rintf(d);                   // nearest-even, matches jnp.round
    float t = d - rn;
    float e2 = __builtin_amdgcn_exp2f(K_EXP2 * t);
    float th = (e2 - 1.0f) * __builtin_amdgcn_rcpf(e2 + 1.0f);
    return x + qh * th;
}

// compiler-only fence: forbids reordering LDS ops across it (zero instructions).
// HW DS pipe is in-order per wave, so this is all the ordering we need.
#define LDS_FENCE() asm volatile("" ::: "memory")

// One wave = one 64x8 tile, 3 channels serial, written out explicitly.
// Zero __syncthreads. Skew-9 transpose (R6/R7/R9-proven):
//   write xp[j*72 + blk*9 + row], read xp[row*72 + blk*9 + k] - both ~2-way max.
// qh/rq in a 1KB LDS table (not registers: R9 showed 32 reg-q VGPRs drop the
// occupancy bucket 8->4 waves/SIMD). Reads are row-broadcast float4s.
__global__ __launch_bounds__(256) void jpeg_kernel(const float* __restrict__ x,
                                                   float* __restrict__ out) {
    __shared__ float xpose[4][576];   // per-wave transpose scratch (9216 B)
    __shared__ float qtab[4][64];     // 0:qhL 1:rqL 2:qhC 3:rqC, [v*8+u]

    const int tid = threadIdx.x;
    const int wid = tid >> 6;
    const int lane = tid & 63;

    const int gw = blockIdx.x * 4 + wid;     // 0..16383
    const int bimg = gw >> 9;                // image
    const int rem = gw & 511;
    const int gh = rem >> 3;                 // 8-row strip index
    const int tx = rem & 7;                  // 64-col tile index

    const int blk = lane & 7;                // 8x8 block within tile
    const int row = lane >> 3;               // row within strip / freq v

    const size_t off = (size_t)bimg * 3 * IMG_HW +
                       (size_t)(gh * 8 + row) * IMG_W + tx * 64 + blk * 8;
    const float* base = x + off;

    // issue global loads first; qtab init overlaps their latency
    const f8v Rv = *(const f8v*)(base);
    const f8v Gv = *(const f8v*)(base + IMG_HW);
    const f8v Bv = *(const f8v*)(base + 2 * IMG_HW);

    // qtab init: every wave duplicate-writes identical values (benign race,
    // R6-proven); each wave reads only after its own writes (in-order DS).
    {
        int u = lane & 7, v = lane >> 3;     // qtab[.][v*8+u] = f(Q[u][v])
        float ql = QLUM[u * 8 + v];
        float qc = QCHR[u * 8 + v];
        qtab[0][lane] = 0.5f * ql;
        qtab[1][lane] = __builtin_amdgcn_rcpf(ql);
        qtab[2][lane] = 0.5f * qc;
        qtab[3][lane] = __builtin_amdgcn_rcpf(qc);
    }
    LDS_FENCE();

    float* xp = xpose[wid];
    const int wbase = blk * 9 + row;         // write: xp[j*72 + wbase]
    const int rbase = row * 72 + blk * 9;    // read:  xp[rbase + k]
    const int qrow = row * 8;

    // ---- forward color (all channels, in regs) ----
    float g0[8], g1[8], g2[8];
#pragma unroll
    for (int k = 0; k < 8; ++k) {
        float R = Rv[k], G = Gv[k], B = Bv[k];
        g0[k] = 0.299f * R + 0.587f * G + 0.114f * B - 0.5f;
        g1[k] = -0.168736f * R - 0.331264f * G + 0.5f * B;
        g2[k] = 0.5f * R - 0.418688f * G - 0.081312f * B;
    }

    // ================= channel 0 (luma) =================
    fdct8(g0);
#pragma unroll
    for (int j = 0; j < 8; ++j) xp[j * 72 + wbase] = g0[j];
    LDS_FENCE();
#pragma unroll
    for (int k = 0; k < 8; ++k) g0[k] = xp[rbase + k];
    LDS_FENCE();
    fdct8(g0);
    {
        float4 qa = *(const float4*)&qtab[0][qrow];
        float4 qb = *(const float4*)&qtab[0][qrow + 4];
        float4 ra = *(const float4*)&qtab[1][qrow];
        float4 rb = *(const float4*)&qtab[1][qrow + 4];
        g0[0] = softq(g0[0], qa.x, ra.x); g0[1] = softq(g0[1], qa.y, ra.y);
        g0[2] = softq(g0[2], qa.z, ra.z); g0[3] = softq(g0[3], qa.w, ra.w);
        g0[4] = softq(g0[4], qb.x, rb.x); g0[5] = softq(g0[5], qb.y, rb.y);
        g0[6] = softq(g0[6], qb.z, rb.z); g0[7] = softq(g0[7], qb.w, rb.w);
    }
    idct8(g0);
    LDS_FENCE();
#pragma unroll
    for (int j = 0; j < 8; ++j) xp[j * 72 + wbase] = g0[j];
    LDS_FENCE();
#pragma unroll
    for (int k = 0; k < 8; ++k) g0[k] = xp[rbase + k];
    LDS_FENCE();
    idct8(g0);

    // ================= channel 1 (Cb) =================
    fdct8(g1);
#pragma unroll
    for (int j = 0; j < 8; ++j) xp[j * 72 + wbase] = g1[j];
    LDS_FENCE();
#pragma unroll
    for (int k = 0; k < 8; ++k) g1[k] = xp[rbase + k];
    LDS_FENCE();
    fdct8(g1);
    {
        float4 qa = *(const float4*)&qtab[2][qrow];
        float4 qb = *(const float4*)&qtab[2][qrow + 4];
        float4 ra = *(const float4*)&qtab[3][qrow];
        float4 rb = *(const float4*)&qtab[3][qrow + 4];
        g1[0] = softq(g1[0], qa.x, ra.x); g1[1] = softq(g1[1], qa.y, ra.y);
        g1[2] = softq(g1[2], qa.z, ra.z); g1[3] = softq(g1[3], qa.w, ra.w);
        g1[4] = softq(g1[4], qb.x, rb.x); g1[5] = softq(g1[5], qb.y, rb.y);
        g1[6] = softq(g1[6], qb.z, rb.z); g1[7] = softq(g1[7], qb.w, rb.w);
    }
    idct8(g1);
    LDS_FENCE();
#pragma unroll
    for (int j = 0; j < 8; ++j) xp[j * 72 + wbase] = g1[j];
    LDS_FENCE();
#pragma unroll
    for (int k = 0; k < 8; ++k) g1[k] = xp[rbase + k];
    LDS_FENCE();
    idct8(g1);

    // ================= channel 2 (Cr) =================
    fdct8(g2);
#pragma unroll
    for (int j = 0; j < 8; ++j) xp[j * 72 + wbase] = g2[j];
    LDS_FENCE();
#pragma unroll
    for (int k = 0; k < 8; ++k) g2[k] = xp[rbase + k];
    LDS_FENCE();
    fdct8(g2);
    {
        float4 qa = *(const float4*)&qtab[2][qrow];
        float4 qb = *(const float4*)&qtab[2][qrow + 4];
        float4 ra = *(const float4*)&qtab[3][qrow];
        float4 rb = *(const float4*)&qtab[3][qrow + 4];
        g2[0] = softq(g2[0], qa.x, ra.x); g2[1] = softq(g2[1], qa.y, ra.y);
        g2[2] = softq(g2[2], qa.z, ra.z); g2[3] = softq(g2[3], qa.w, ra.w);
        g2[4] = softq(g2[4], qb.x, rb.x); g2[5] = softq(g2[5], qb.y, rb.y);
        g2[6] = softq(g2[6], qb.z, rb.z); g2[7] = softq(g2[7], qb.w, rb.w);
    }
    idct8(g2);
    LDS_FENCE();
#pragma unroll
    for (int j = 0; j < 8; ++j) xp[j * 72 + wbase] = g2[j];
    LDS_FENCE();
#pragma unroll
    for (int k = 0; k < 8; ++k) g2[k] = xp[rbase + k];
    LDS_FENCE();
    idct8(g2);

    // ---- inverse color + coalesced stores ----
    f8v Ro, Go, Bo;
#pragma unroll
    for (int k = 0; k < 8; ++k) {
        float Y  = g0[k] + 0.5f;
        float Cb = g1[k];
        float Cr = g2[k];
        float R = Y + 1.402f * Cr;
        float G = Y - 0.344136f * Cb - 0.714136f * Cr;
        float B = Y + 1.772f * Cb;
        Ro[k] = fminf(fmaxf(R, 0.0f), 1.0f);
        Go[k] = fminf(fmaxf(G, 0.0f), 1.0f);
        Bo[k] = fminf(fmaxf(B, 0.0f), 1.0f);
    }
    float* obase = out + off;
    *(f8v*)(obase) = Ro;
    *(f8v*)(obase + IMG_HW) = Go;
    *(f8v*)(obase + 2 * IMG_HW) = Bo;
}

extern "C" void kernel_launch(void* const* d_in, const int* in_sizes, int n_in,
                              void* d_out, int out_size, void* d_ws, size_t ws_size,
                              hipStream_t stream) {
    const float* x = (const float*)d_in[0];
    float* out = (float*)d_out;
    const int B = in_sizes[0] / (3 * IMG_HW);   // 32
    const int n_wg = B * 128;                   // one tile per wave, 4 waves/WG
    hipLaunchKernelGGL(jpeg_kernel, dim3(n_wg), dim3(256), 0, stream, x, out);
}